// Round 2
// baseline (1788.800 us; speedup 1.0000x reference)
//
#include <hip/hip_runtime.h>
#include <math.h>

// DisenTripletGCN — f32-compute / bf16-storage baseline, compact workspace.
// O=20000 objects, T=80000 edges, D=512 (8 caps x 64), NLAYER=2, ROUTIT=3.
//
// ws layout (bytes):
//   Xh  @ 0          : 80000*512 bf16 = 81,920,000   (edge feats post-pca+l2norm; reused phase 2)
//   Uh1 @ 81920000   : 20000*512 bf16 = 20,480,000
//   Uh2 @ 102400000  : 20000*512 bf16 = 20,480,000
//   PL  @ 122880000  : 20000*256 f32  = 20,480,000   (pooled accumulators, atomicAdd)
//   I   @ 143360000  : 280,002 ints   =  1,120,008   (CSR)
// total = 144,480,008 B (~138 MiB)  [round-0's 431 MB likely overflowed ws -> GPU fault]

#define O_N 20000
#define T_N 80000

typedef unsigned short bf_t;
typedef bf_t bfx4 __attribute__((ext_vector_type(4)));
typedef bf_t bfx8 __attribute__((ext_vector_type(8)));

__device__ __forceinline__ float leaky(float y) { return y > 0.0f ? y : 0.01f * y; }

__device__ __forceinline__ float bf2f(bf_t u) {
  union { unsigned int i; float f; } v; v.i = ((unsigned int)u) << 16; return v.f;
}
__device__ __forceinline__ bf_t f2bf(float f) {
  union { float f; unsigned int i; } v; v.f = f;
  unsigned int b = v.i;
  return (bf_t)((b + 0x7FFFu + ((b >> 16) & 1u)) >> 16);  // RNE
}

// ---------------- CSR build ----------------
__global__ void count_kernel(const int* __restrict__ edges, int* cnt_s, int* cnt_o) {
  int m = blockIdx.x * blockDim.x + threadIdx.x;
  if (m < T_N) {
    atomicAdd(&cnt_s[edges[2 * m]], 1);
    atomicAdd(&cnt_o[edges[2 * m + 1]], 1);
  }
}

__global__ void scan_kernel(const int* __restrict__ cnt_s, const int* __restrict__ cnt_o,
                            int* offs_s, int* cur_s, int* offs_o, int* cur_o) {
  const int n = O_N;
  const int* cnt = (blockIdx.x == 0) ? cnt_s : cnt_o;
  int* offs = (blockIdx.x == 0) ? offs_s : offs_o;
  int* cur  = (blockIdx.x == 0) ? cur_s  : cur_o;
  __shared__ int lds[1024];
  __shared__ int sbase;
  if (threadIdx.x == 0) sbase = 0;
  __syncthreads();
  for (int start = 0; start < n; start += 1024) {
    int i = start + (int)threadIdx.x;
    int v = (i < n) ? cnt[i] : 0;
    lds[threadIdx.x] = v;
    __syncthreads();
    for (int off = 1; off < 1024; off <<= 1) {
      int t = (threadIdx.x >= (unsigned)off) ? lds[threadIdx.x - off] : 0;
      __syncthreads();
      lds[threadIdx.x] += t;
      __syncthreads();
    }
    int base = sbase;
    int excl = base + lds[threadIdx.x] - v;
    if (i < n) { offs[i] = excl; cur[i] = excl; }
    __syncthreads();
    if (threadIdx.x == 1023) sbase = base + lds[1023];
    __syncthreads();
  }
  if (threadIdx.x == 0) offs[n] = sbase;
}

__global__ void fill_kernel(const int* __restrict__ edges, int* cur_s, int* cur_o,
                            int* eid_s, int* eid_o) {
  int m = blockIdx.x * blockDim.x + threadIdx.x;
  if (m < T_N) {
    int s = edges[2 * m], o = edges[2 * m + 1];
    eid_s[atomicAdd(&cur_s[s], 1)] = m;
    eid_o[atomicAdd(&cur_o[o], 1)] = m;
  }
}

// ---------------- GEMM 64x64x16, 4x4 micro, f32 compute ----------------
// MODE 0 (pca1): A = gathered [obj[s]|pred|obj[o]] f32, K=384; epi: +b, leaky,
//                fused per-capsule l2norm (64-col block == 1 capsule) -> Xh bf16
// MODE 1 (clf1): A row m: (m<O_N ? Uh2 : Xh) bf16, K=512, N=768; epi: bn+leaky;
//                n<256 -> atomicAdd PL[s*256+n]; 256..511 -> pred_out; >=512 -> atomicAdd PL[o*256+n-512]
// MODE 2 (pca2): A = PL f32 (K=256), M-guard; epi like MODE 0 -> Xh bf16
// MODE 3 (clf2): A = Uh2 bf16 (K=512), M-guard; epi: bn+leaky -> obj_out f32
template <int MODE>
__global__ __launch_bounds__(256) void gemm64(
    const bf_t* __restrict__ Ah, const bf_t* __restrict__ Axh,
    const float* __restrict__ Af,
    const float* __restrict__ obj, const float* __restrict__ pred,
    const int* __restrict__ edges,
    const float* __restrict__ W, const float* __restrict__ bias,
    const float* __restrict__ bng, const float* __restrict__ bnb,
    bf_t* __restrict__ outh, float* __restrict__ outf, float* __restrict__ pool,
    int M, int N, int K) {
  __shared__ float As[16][68];
  __shared__ float Bs[16][64];
  __shared__ int sE[64][2];
  const int tid = threadIdx.x;
  const int row0 = blockIdx.y * 64, col0 = blockIdx.x * 64;
  if (MODE == 0 || MODE == 1) {
    if (tid < 128) sE[tid >> 1][tid & 1] = edges[2 * (row0 + (tid >> 1)) + (tid & 1)];
    __syncthreads();
  }
  const int tm = tid >> 4, tn = tid & 15;
  const int lr = tid >> 2, lq = tid & 3;
  float acc[4][4] = {};
  for (int k0 = 0; k0 < K; k0 += 16) {
    float a0, a1, a2, a3;
    int m = row0 + lr;
    if (MODE == 0) {
      int c = k0 + lq * 4;
      const float* base;
      if (c < 128)      base = obj  + (size_t)sE[lr][0] * 128 + c;
      else if (c < 256) base = pred + (size_t)m * 128 + (c - 128);
      else              base = obj  + (size_t)sE[lr][1] * 128 + (c - 256);
      float4 av = *(const float4*)base;
      a0 = av.x; a1 = av.y; a2 = av.z; a3 = av.w;
    } else if (MODE == 1) {
      const bf_t* base = ((m < O_N) ? Ah : Axh) + (size_t)m * 512 + k0 + lq * 4;
      bfx4 av = *(const bfx4*)base;
      a0 = bf2f(av[0]); a1 = bf2f(av[1]); a2 = bf2f(av[2]); a3 = bf2f(av[3]);
    } else if (MODE == 2) {
      if (m < M) {
        float4 av = *(const float4*)(Af + (size_t)m * K + k0 + lq * 4);
        a0 = av.x; a1 = av.y; a2 = av.z; a3 = av.w;
      } else { a0 = a1 = a2 = a3 = 0.0f; }
    } else {
      if (m < M) {
        bfx4 av = *(const bfx4*)(Ah + (size_t)m * 512 + k0 + lq * 4);
        a0 = bf2f(av[0]); a1 = bf2f(av[1]); a2 = bf2f(av[2]); a3 = bf2f(av[3]);
      } else { a0 = a1 = a2 = a3 = 0.0f; }
    }
    float4 bv = *(const float4*)(W + (size_t)(k0 + tm) * N + col0 + tn * 4);
    __syncthreads();
    As[lq * 4 + 0][lr] = a0; As[lq * 4 + 1][lr] = a1;
    As[lq * 4 + 2][lr] = a2; As[lq * 4 + 3][lr] = a3;
    *(float4*)&Bs[tm][tn * 4] = bv;
    __syncthreads();
#pragma unroll
    for (int k = 0; k < 16; ++k) {
      float4 a4 = *(const float4*)&As[k][tm * 4];
      float4 b4 = *(const float4*)&Bs[k][tn * 4];
      acc[0][0] += a4.x * b4.x; acc[0][1] += a4.x * b4.y; acc[0][2] += a4.x * b4.z; acc[0][3] += a4.x * b4.w;
      acc[1][0] += a4.y * b4.x; acc[1][1] += a4.y * b4.y; acc[1][2] += a4.y * b4.z; acc[1][3] += a4.y * b4.w;
      acc[2][0] += a4.z * b4.x; acc[2][1] += a4.z * b4.y; acc[2][2] += a4.z * b4.z; acc[2][3] += a4.z * b4.w;
      acc[3][0] += a4.w * b4.x; acc[3][1] += a4.w * b4.y; acc[3][2] += a4.w * b4.z; acc[3][3] += a4.w * b4.w;
    }
  }
  const float invs = 1.0f / sqrtf(1.0f + 1e-5f);
  if (MODE == 0 || MODE == 2) {
    // leaky + fused per-capsule l2norm (this block's 64 cols == one capsule)
#pragma unroll
    for (int i = 0; i < 4; ++i) {
      float yv[4];
      float ssq = 0.0f;
#pragma unroll
      for (int j = 0; j < 4; ++j) {
        float y = acc[i][j] + bias[col0 + tn * 4 + j];
        y = leaky(y);
        yv[j] = y; ssq += y * y;
      }
      ssq += __shfl_xor(ssq, 1); ssq += __shfl_xor(ssq, 2);
      ssq += __shfl_xor(ssq, 4); ssq += __shfl_xor(ssq, 8);
      int m = row0 + tm * 4 + i;
      if (MODE == 2 && m >= M) continue;
      float inv = 1.0f / fmaxf(sqrtf(ssq), 1e-12f);
      bfx4 o;
      o[0] = f2bf(yv[0] * inv); o[1] = f2bf(yv[1] * inv);
      o[2] = f2bf(yv[2] * inv); o[3] = f2bf(yv[3] * inv);
      *(bfx4*)(outh + (size_t)m * 512 + col0 + tn * 4) = o;
    }
  } else if (MODE == 1) {
#pragma unroll
    for (int i = 0; i < 4; ++i) {
      int m = row0 + tm * 4 + i;
      int es = sE[tm * 4 + i][0], eo = sE[tm * 4 + i][1];
#pragma unroll
      for (int j = 0; j < 4; ++j) {
        int n = col0 + tn * 4 + j;
        float y = (acc[i][j] + bias[n]) * (bng[n] * invs) + bnb[n];
        y = leaky(y);
        if (n < 256)      atomicAdd(&pool[(size_t)es * 256 + n], y);
        else if (n < 512) outf[(size_t)m * 256 + (n - 256)] = y;
        else              atomicAdd(&pool[(size_t)eo * 256 + (n - 512)], y);
      }
    }
  } else {
#pragma unroll
    for (int i = 0; i < 4; ++i) {
      int m = row0 + tm * 4 + i;
      if (m >= M) continue;
#pragma unroll
      for (int j = 0; j < 4; ++j) {
        int n = col0 + tn * 4 + j;
        float y = (acc[i][j] + bias[n]) * (bng[n] * invs) + bnb[n];
        outf[(size_t)m * 256 + n] = leaky(y);
      }
    }
  }
}

// ---------------- fused routing layer: wave per node, 3 iters in-register ----------------
__global__ __launch_bounds__(256) void rout_layer(
    const bf_t* __restrict__ Z, bf_t* __restrict__ U,
    const int* __restrict__ offs, const int* __restrict__ eid,
    const int* __restrict__ edges, int nnodes) {
  int v = blockIdx.x * 4 + ((int)threadIdx.x >> 6);
  int lane = threadIdx.x & 63;
  if (v >= nnodes) return;
  bfx8 xv = *(const bfx8*)(Z + (size_t)v * 512 + lane * 8);
  float xr[8], ur[8];
#pragma unroll
  for (int q = 0; q < 8; ++q) { xr[q] = bf2f(xv[q]); ur[q] = xr[q]; }
  int e0 = offs[v], e1 = offs[v + 1];
  for (int it = 0; it < 3; ++it) {
    float ag[8] = {0, 0, 0, 0, 0, 0, 0, 0};
    for (int e = e0; e < e1; ++e) {
      int mm = eid[e];
      bfx8 zv = *(const bfx8*)(Z + (size_t)edges[2 * mm] * 512 + lane * 8);
      float zr[8];
      float d = 0.0f;
#pragma unroll
      for (int q = 0; q < 8; ++q) { zr[q] = bf2f(zv[q]); d += zr[q] * ur[q]; }
      d += __shfl_xor(d, 1); d += __shfl_xor(d, 2); d += __shfl_xor(d, 4);
      float mx = d;
      mx = fmaxf(mx, __shfl_xor(mx, 8));
      mx = fmaxf(mx, __shfl_xor(mx, 16));
      mx = fmaxf(mx, __shfl_xor(mx, 32));
      float ex = expf(d - mx);
      float sm = ex;
      sm += __shfl_xor(sm, 8); sm += __shfl_xor(sm, 16); sm += __shfl_xor(sm, 32);
      float pk = ex / sm;
#pragma unroll
      for (int q = 0; q < 8; ++q) ag[q] += pk * zr[q];
    }
    float ss = 0.0f;
    float wv[8];
#pragma unroll
    for (int q = 0; q < 8; ++q) { wv[q] = ag[q] + xr[q]; ss += wv[q] * wv[q]; }
    ss += __shfl_xor(ss, 1); ss += __shfl_xor(ss, 2); ss += __shfl_xor(ss, 4);
    float inv = 1.0f / fmaxf(sqrtf(ss), 1e-12f);
#pragma unroll
    for (int q = 0; q < 8; ++q) ur[q] = wv[q] * inv;
  }
  bfx8 ov;
#pragma unroll
  for (int q = 0; q < 8; ++q) ov[q] = f2bf(ur[q]);
  *(bfx8*)(U + (size_t)v * 512 + lane * 8) = ov;
}

// ---------------- pooled /= max(degree,1) (degree from CSR offsets) ----------------
__global__ void divide_kernel(float* __restrict__ PL,
                              const int* __restrict__ offs_s, const int* __restrict__ offs_o) {
  int v = blockIdx.x;
  int c = threadIdx.x;
  float cnt = (float)((offs_s[v + 1] - offs_s[v]) + (offs_o[v + 1] - offs_o[v]));
  float inv = 1.0f / fmaxf(cnt, 1.0f);
  PL[(size_t)v * 256 + c] *= inv;
}

extern "C" void kernel_launch(void* const* d_in, const int* in_sizes, int n_in,
                              void* d_out, int out_size, void* d_ws, size_t ws_size,
                              hipStream_t stream) {
  const float* obj    = (const float*)d_in[0];
  const float* pred   = (const float*)d_in[1];
  const int*   edges  = (const int*)d_in[2];
  const float* pca_w1 = (const float*)d_in[3];
  const float* pca_b1 = (const float*)d_in[4];
  const float* clf_w1 = (const float*)d_in[5];
  const float* clf_b1 = (const float*)d_in[6];
  const float* bn_g1  = (const float*)d_in[7];
  const float* bn_b1  = (const float*)d_in[8];
  const float* pca_w2 = (const float*)d_in[9];
  const float* pca_b2 = (const float*)d_in[10];
  const float* clf_w2 = (const float*)d_in[11];
  const float* clf_b2 = (const float*)d_in[12];
  const float* bn_g2  = (const float*)d_in[13];
  const float* bn_b2  = (const float*)d_in[14];
  float* outp = (float*)d_out;

  char* ws = (char*)d_ws;
  bf_t* Xh   = (bf_t*)ws;
  bf_t* Uh1  = (bf_t*)(ws + 81920000);
  bf_t* Uh2  = (bf_t*)(ws + 102400000);
  float* PL  = (float*)(ws + 122880000);
  int* I     = (int*)(ws + 143360000);
  int* cnt_s = I;            int* cnt_o = I + 20000;
  int* offs_s = I + 40000;   int* offs_o = I + 60001;
  int* cur_s = I + 80002;    int* cur_o = I + 100002;
  int* eid_s = I + 120002;   int* eid_o = I + 200002;

  // zero PL + cnt_s + cnt_o (contiguous)
  hipMemsetAsync(PL, 0, 20480000 + 160000, stream);

  count_kernel<<<313, 256, 0, stream>>>(edges, cnt_s, cnt_o);
  scan_kernel<<<2, 1024, 0, stream>>>(cnt_s, cnt_o, offs_s, cur_s, offs_o, cur_o);
  fill_kernel<<<313, 256, 0, stream>>>(edges, cur_s, cur_o, eid_s, eid_o);

  // ---- phase 1 ----
  gemm64<0><<<dim3(8, 1250), 256, 0, stream>>>(nullptr, nullptr, nullptr, obj, pred, edges,
                                               pca_w1, pca_b1, nullptr, nullptr,
                                               Xh, nullptr, nullptr, T_N, 512, 384);
  rout_layer<<<5000, 256, 0, stream>>>(Xh, Uh1, offs_o, eid_o, edges, O_N);
  rout_layer<<<5000, 256, 0, stream>>>(Uh1, Uh2, offs_o, eid_o, edges, O_N);
  gemm64<1><<<dim3(12, 1250), 256, 0, stream>>>(Uh2, Xh, nullptr, nullptr, nullptr, edges,
                                                clf_w1, clf_b1, bn_g1, bn_b1,
                                                nullptr, outp + 5120000, PL, T_N, 768, 512);
  divide_kernel<<<O_N, 256, 0, stream>>>(PL, offs_s, offs_o);

  // ---- phase 2 (Xh reused) ----
  gemm64<2><<<dim3(8, 313), 256, 0, stream>>>(nullptr, nullptr, PL, nullptr, nullptr, nullptr,
                                              pca_w2, pca_b2, nullptr, nullptr,
                                              Xh, nullptr, nullptr, O_N, 512, 256);
  rout_layer<<<5000, 256, 0, stream>>>(Xh, Uh1, offs_o, eid_o, edges, O_N);
  rout_layer<<<5000, 256, 0, stream>>>(Uh1, Uh2, offs_o, eid_o, edges, O_N);
  gemm64<3><<<dim3(4, 313), 256, 0, stream>>>(Uh2, nullptr, nullptr, nullptr, nullptr, nullptr,
                                              clf_w2, clf_b2, bn_g2, bn_b2,
                                              nullptr, outp, nullptr, O_N, 256, 512);
}

// Round 4
// 773.323 us; speedup vs baseline: 2.3131x; 2.3131x over previous
//
#include <hip/hip_runtime.h>
#include <math.h>

// DisenTripletGCN — MFMA bf16 GEMMs + f32 routing.  (Resubmission of round-3
// kernel: round-3 bench died at container level with no pytest output —
// infra flake suspected; kernel audit found no fault/hang class.)
// ws layout (bytes):
//   Xh   @ 0           : 80000*512 bf16 = 81,920,000
//   Uh2  @ 81,920,000  : 20000*512 bf16 = 20,480,000
//   PL/Uh1 @102,400,000: 20000*256 f32  = 20,480,000  (Uh1 bf16 overlays PL; lifetimes disjoint)
//   Wt1  @122,880,000  : 512x384 bf16   (pca_w1^T)
//   Wt2  @123,273,216  : 768x512 bf16   (clf_w1^T)
//   Wt3  @124,059,648  : 512x256 bf16   (pca_w2^T)
//   Wt4  @124,321,792  : 256x512 bf16   (clf_w2^T)
//   I    @124,583,936  : 180,002 ints (CSR)
// total ~119.9 MiB (< proven 144.5 MiB budget)

#define O_N 20000
#define T_N 80000

typedef unsigned short bf_t;
typedef bf_t bfx8 __attribute__((ext_vector_type(8)));
typedef __attribute__((ext_vector_type(4))) float f32x4;
typedef __attribute__((ext_vector_type(8))) short s16x8;

#define AS1 __attribute__((address_space(1)))
#define AS3 __attribute__((address_space(3)))

__device__ __forceinline__ float leaky(float y) { return y > 0.0f ? y : 0.01f * y; }
__device__ __forceinline__ float bf2f(bf_t u) {
  union { unsigned int i; float f; } v; v.i = ((unsigned int)u) << 16; return v.f;
}
__device__ __forceinline__ bf_t f2bf(float f) {
  union { float f; unsigned int i; } v; v.f = f;
  unsigned int b = v.i;
  return (bf_t)((b + 0x7FFFu + ((b >> 16) & 1u)) >> 16);  // RNE
}
__device__ __forceinline__ void gload16(const bf_t* g, bf_t* l) {
  __builtin_amdgcn_global_load_lds((const AS1 void*)g, (AS3 void*)l, 16, 0, 0);
}

// ---------------- CSR build ----------------
__global__ void count_kernel(const int* __restrict__ edges, int* cnt_s, int* cnt_o) {
  int m = blockIdx.x * blockDim.x + threadIdx.x;
  if (m < T_N) {
    atomicAdd(&cnt_s[edges[2 * m]], 1);
    atomicAdd(&cnt_o[edges[2 * m + 1]], 1);
  }
}

__global__ void scan_kernel(const int* __restrict__ cnt_s, const int* __restrict__ cnt_o,
                            int* offs_s, int* offs_o, int* cur_o) {
  const int n = O_N;
  const int* cnt = (blockIdx.x == 0) ? cnt_s : cnt_o;
  int* offs = (blockIdx.x == 0) ? offs_s : offs_o;
  int* cur  = (blockIdx.x == 0) ? nullptr : cur_o;
  __shared__ int lds[1024];
  __shared__ int sbase;
  if (threadIdx.x == 0) sbase = 0;
  __syncthreads();
  for (int start = 0; start < n; start += 1024) {
    int i = start + (int)threadIdx.x;
    int v = (i < n) ? cnt[i] : 0;
    lds[threadIdx.x] = v;
    __syncthreads();
    for (int off = 1; off < 1024; off <<= 1) {
      int t = (threadIdx.x >= (unsigned)off) ? lds[threadIdx.x - off] : 0;
      __syncthreads();
      lds[threadIdx.x] += t;
      __syncthreads();
    }
    int base = sbase;
    int excl = base + lds[threadIdx.x] - v;
    if (i < n) { offs[i] = excl; if (cur) cur[i] = excl; }
    __syncthreads();
    if (threadIdx.x == 1023) sbase = base + lds[1023];
    __syncthreads();
  }
  if (threadIdx.x == 0) offs[n] = sbase;
}

__global__ void fill_kernel(const int* __restrict__ edges, int* cur_o, int* srcs) {
  int m = blockIdx.x * blockDim.x + threadIdx.x;
  if (m < T_N) {
    int s = edges[2 * m], o = edges[2 * m + 1];
    srcs[atomicAdd(&cur_o[o], 1)] = s;
  }
}

// ---------------- weight transpose + cvt: W[K][N] f32 -> Wt[N][K] bf16 ----------------
__global__ void transpose_cvt(const float* __restrict__ W, bf_t* __restrict__ Wt, int K, int N) {
  __shared__ float t[32][33];
  int kb = blockIdx.y << 5, nb = blockIdx.x << 5;
  int tx = threadIdx.x, ty = threadIdx.y;  // 32 x 8
#pragma unroll
  for (int r = 0; r < 32; r += 8) t[ty + r][tx] = W[(size_t)(kb + ty + r) * N + nb + tx];
  __syncthreads();
#pragma unroll
  for (int r = 0; r < 32; r += 8) Wt[(size_t)(nb + ty + r) * K + kb + tx] = f2bf(t[tx][ty + r]);
}

// ---------------- MFMA GEMM: C[M,N] = A[M,K](bf16) x Wt[N,K](bf16), 128x128 tile ----------------
// MODE 0 (pca1): A gathered [obj[s]|pred|obj[o]] f32 reg-staged; epi: +b, leaky, capsule-l2norm -> Xh
// MODE 1 (clf1): A = m<O_N ? Uh2 : Xh (bf16, DMA); epi: bn+leaky; n<256 -> atomicAdd PL[s],
//                256..511 -> pred_out, >=512 -> atomicAdd PL[o]
// MODE 2 (pca2): A = PL f32 reg-staged (M-guard); epi like MODE 0 -> Xh
// MODE 3 (clf2): A = Uh2 bf16 DMA (M-guard); epi: bn+leaky -> obj_out f32
template <int MODE>
__global__ __launch_bounds__(256) void gemm_mfma(
    const bf_t* __restrict__ Ah, const bf_t* __restrict__ Axh,
    const float* __restrict__ Af,
    const float* __restrict__ obj, const float* __restrict__ pred,
    const int* __restrict__ edges,
    const bf_t* __restrict__ Wt, const float* __restrict__ bias,
    const float* __restrict__ bng, const float* __restrict__ bnb,
    bf_t* __restrict__ outh, float* __restrict__ outf, float* __restrict__ pool,
    int M, int N, int K) {
  constexpr bool REG = (MODE == 0 || MODE == 2);   // reg-staged f32 A
  constexpr int ASTR = REG ? 40 : 32;              // A LDS row stride (shorts)
  __shared__ __align__(16) bf_t As[128 * ASTR];
  __shared__ __align__(16) bf_t Bs[128 * 32];
  __shared__ int sE[256];

  const int tid = threadIdx.x;
  const int w = tid >> 6, l = tid & 63;
  const int wr = w >> 1, wc = w & 1;
  const int row0 = blockIdx.y * 128, col0 = blockIdx.x * 128;

  // --- prologue: per-lane staging pointers ---
  const int srow = l >> 2;  // row within a wave's 16-row DMA chunk
  const int skb = ((l & 3) ^ ((l >> 2) & 3) ^ ((l >> 4) & 3)) * 8;  // swizzled src k-offset
  const bf_t* pB[2];
  bf_t* ldsB[2];
  bf_t* ldsA[2];
  const bf_t* pA[2];
#pragma unroll
  for (int j = 0; j < 2; ++j) {
    int n = col0 + j * 64 + w * 16 + srow;
    pB[j] = Wt + (size_t)n * K + skb;
    ldsB[j] = Bs + (j * 64 + w * 16) * 32;
    ldsA[j] = As + (j * 64 + w * 16) * 32;
  }
  if constexpr (MODE == 1 || MODE == 3) {
#pragma unroll
    for (int j = 0; j < 2; ++j) {
      int m = row0 + j * 64 + w * 16 + srow;
      if (MODE == 3) m = min(m, M - 1);
      const bf_t* base = (MODE == 1) ? ((m < O_N) ? Ah : Axh) : Ah;
      pA[j] = base + (size_t)m * 512 + skb;
    }
  }
  int sIdx = 0, oIdx = 0, mrow = 0;
  if constexpr (MODE == 0) {
    mrow = row0 + (tid >> 1);
    sIdx = edges[2 * mrow];
    oIdx = edges[2 * mrow + 1];
  }
  if constexpr (MODE == 2) mrow = min(row0 + (tid >> 1), M - 1);
  if constexpr (MODE == 1) sE[tid] = edges[2 * row0 + tid];

  // --- fragment read offsets (elements) ---
  const int pkb = ((l >> 4) ^ (l & 3) ^ ((l >> 2) & 3)) * 8;
  int aoff[4], boff[4];
#pragma unroll
  for (int i = 0; i < 4; ++i) {
    int ar = wr * 64 + i * 16 + (l & 15);
    aoff[i] = REG ? (ar * 40 + (l >> 4) * 8) : (ar * 32 + pkb);
    int bn = wc * 64 + i * 16 + (l & 15);
    boff[i] = bn * 32 + pkb;
  }

  f32x4 acc[4][4];
  const f32x4 z4 = {0.f, 0.f, 0.f, 0.f};
#pragma unroll
  for (int i = 0; i < 4; ++i)
#pragma unroll
    for (int j = 0; j < 4; ++j) acc[i][j] = z4;

  // --- K loop ---
  for (int k0 = 0; k0 < K; k0 += 32) {
    if (k0) __syncthreads();
#pragma unroll
    for (int j = 0; j < 2; ++j) { gload16(pB[j], ldsB[j]); pB[j] += 32; }
    if constexpr (MODE == 1 || MODE == 3) {
#pragma unroll
      for (int j = 0; j < 2; ++j) { gload16(pA[j], ldsA[j]); pA[j] += 32; }
    } else {
      int r = tid >> 1, h = tid & 1;
      int c = k0 + h * 16;
      const float* base;
      if constexpr (MODE == 0) {
        if (c < 128)      base = obj  + (size_t)sIdx * 128 + c;
        else if (c < 256) base = pred + (size_t)mrow * 128 + (c - 128);
        else              base = obj  + (size_t)oIdx * 128 + (c - 256);
      } else {
        base = Af + (size_t)mrow * K + c;
      }
      float4 q0 = ((const float4*)base)[0];
      float4 q1 = ((const float4*)base)[1];
      float4 q2 = ((const float4*)base)[2];
      float4 q3 = ((const float4*)base)[3];
      bf_t* d = As + r * 40 + h * 16;
      bfx8 w0, w1;
      w0[0] = f2bf(q0.x); w0[1] = f2bf(q0.y); w0[2] = f2bf(q0.z); w0[3] = f2bf(q0.w);
      w0[4] = f2bf(q1.x); w0[5] = f2bf(q1.y); w0[6] = f2bf(q1.z); w0[7] = f2bf(q1.w);
      w1[0] = f2bf(q2.x); w1[1] = f2bf(q2.y); w1[2] = f2bf(q2.z); w1[3] = f2bf(q2.w);
      w1[4] = f2bf(q3.x); w1[5] = f2bf(q3.y); w1[6] = f2bf(q3.z); w1[7] = f2bf(q3.w);
      *(bfx8*)d = w0;
      *(bfx8*)(d + 8) = w1;
    }
    __syncthreads();
    s16x8 a[4], b[4];
#pragma unroll
    for (int i = 0; i < 4; ++i) a[i] = *(const s16x8*)(As + aoff[i]);
#pragma unroll
    for (int i = 0; i < 4; ++i) b[i] = *(const s16x8*)(Bs + boff[i]);
#pragma unroll
    for (int mi = 0; mi < 4; ++mi)
#pragma unroll
      for (int ni = 0; ni < 4; ++ni)
        acc[mi][ni] = __builtin_amdgcn_mfma_f32_16x16x32_bf16(a[mi], b[ni], acc[mi][ni], 0, 0, 0);
  }

  // --- epilogue ---
  const int lg = l >> 4, li = l & 15;
  const float invs = 1.0f / sqrtf(1.0f + 1e-5f);
  int ncol[4];
  float bsv[4], bgv[4], bbv[4];
#pragma unroll
  for (int ni = 0; ni < 4; ++ni) {
    int n = col0 + wc * 64 + ni * 16 + li;
    ncol[ni] = n;
    bsv[ni] = bias[n];
    if constexpr (MODE == 1 || MODE == 3) { bgv[ni] = bng[n] * invs; bbv[ni] = bnb[n]; }
  }
  if constexpr (MODE == 0 || MODE == 2) {
#pragma unroll
    for (int mi = 0; mi < 4; ++mi) {
#pragma unroll
      for (int rg = 0; rg < 4; ++rg) {
        int m = row0 + wr * 64 + mi * 16 + lg * 4 + rg;
        float y[4], ssq = 0.f;
#pragma unroll
        for (int ni = 0; ni < 4; ++ni) {
          float v = leaky(acc[mi][ni][rg] + bsv[ni]);
          y[ni] = v; ssq += v * v;
        }
        ssq += __shfl_xor(ssq, 1); ssq += __shfl_xor(ssq, 2);
        ssq += __shfl_xor(ssq, 4); ssq += __shfl_xor(ssq, 8);
        if (MODE == 2 && m >= M) continue;
        float inv = 1.0f / fmaxf(sqrtf(ssq), 1e-12f);
#pragma unroll
        for (int ni = 0; ni < 4; ++ni)
          outh[(size_t)m * 512 + ncol[ni]] = f2bf(y[ni] * inv);
      }
    }
  } else if constexpr (MODE == 1) {
#pragma unroll
    for (int mi = 0; mi < 4; ++mi) {
#pragma unroll
      for (int rg = 0; rg < 4; ++rg) {
        int rloc = wr * 64 + mi * 16 + lg * 4 + rg;
        int m = row0 + rloc;
        int sI = sE[2 * rloc], oI = sE[2 * rloc + 1];
#pragma unroll
        for (int ni = 0; ni < 4; ++ni) {
          int n = ncol[ni];
          float v = leaky((acc[mi][ni][rg] + bsv[ni]) * bgv[ni] + bbv[ni]);
          if (n < 256)      atomicAdd(&pool[(size_t)sI * 256 + n], v);
          else if (n < 512) outf[(size_t)m * 256 + (n - 256)] = v;
          else              atomicAdd(&pool[(size_t)oI * 256 + (n - 512)], v);
        }
      }
    }
  } else {
#pragma unroll
    for (int mi = 0; mi < 4; ++mi) {
#pragma unroll
      for (int rg = 0; rg < 4; ++rg) {
        int m = row0 + wr * 64 + mi * 16 + lg * 4 + rg;
        if (m >= M) continue;
#pragma unroll
        for (int ni = 0; ni < 4; ++ni) {
          float v = leaky((acc[mi][ni][rg] + bsv[ni]) * bgv[ni] + bbv[ni]);
          outf[(size_t)m * 256 + ncol[ni]] = v;
        }
      }
    }
  }
}

// ---------------- fused routing layer: wave per node, 3 iters in-register ----------------
__global__ __launch_bounds__(256) void rout_layer(
    const bf_t* __restrict__ Z, bf_t* __restrict__ U,
    const int* __restrict__ offs, const int* __restrict__ srcs, int nnodes) {
  int v = blockIdx.x * 4 + ((int)threadIdx.x >> 6);
  int lane = threadIdx.x & 63;
  if (v >= nnodes) return;
  bfx8 xv = *(const bfx8*)(Z + (size_t)v * 512 + lane * 8);
  float xr[8], ur[8];
#pragma unroll
  for (int q = 0; q < 8; ++q) { xr[q] = bf2f(xv[q]); ur[q] = xr[q]; }
  int e0 = offs[v], e1 = offs[v + 1];
  for (int it = 0; it < 3; ++it) {
    float ag[8] = {0, 0, 0, 0, 0, 0, 0, 0};
    for (int e = e0; e < e1; ++e) {
      bfx8 zv = *(const bfx8*)(Z + (size_t)srcs[e] * 512 + lane * 8);
      float zr[8];
      float d = 0.0f;
#pragma unroll
      for (int q = 0; q < 8; ++q) { zr[q] = bf2f(zv[q]); d += zr[q] * ur[q]; }
      d += __shfl_xor(d, 1); d += __shfl_xor(d, 2); d += __shfl_xor(d, 4);
      float mx = d;
      mx = fmaxf(mx, __shfl_xor(mx, 8));
      mx = fmaxf(mx, __shfl_xor(mx, 16));
      mx = fmaxf(mx, __shfl_xor(mx, 32));
      float ex = expf(d - mx);
      float sm = ex;
      sm += __shfl_xor(sm, 8); sm += __shfl_xor(sm, 16); sm += __shfl_xor(sm, 32);
      float pk = ex / sm;
#pragma unroll
      for (int q = 0; q < 8; ++q) ag[q] += pk * zr[q];
    }
    float ss = 0.0f, wv[8];
#pragma unroll
    for (int q = 0; q < 8; ++q) { wv[q] = ag[q] + xr[q]; ss += wv[q] * wv[q]; }
    ss += __shfl_xor(ss, 1); ss += __shfl_xor(ss, 2); ss += __shfl_xor(ss, 4);
    float inv = 1.0f / fmaxf(sqrtf(ss), 1e-12f);
#pragma unroll
    for (int q = 0; q < 8; ++q) ur[q] = wv[q] * inv;
  }
  bfx8 ov;
#pragma unroll
  for (int q = 0; q < 8; ++q) ov[q] = f2bf(ur[q]);
  *(bfx8*)(U + (size_t)v * 512 + lane * 8) = ov;
}

// ---------------- pooled /= max(degree,1) ----------------
__global__ void divide_kernel(float* __restrict__ PL,
                              const int* __restrict__ offs_s, const int* __restrict__ offs_o) {
  int v = blockIdx.x;
  int c = threadIdx.x;
  float cnt = (float)((offs_s[v + 1] - offs_s[v]) + (offs_o[v + 1] - offs_o[v]));
  PL[(size_t)v * 256 + c] *= 1.0f / fmaxf(cnt, 1.0f);
}

extern "C" void kernel_launch(void* const* d_in, const int* in_sizes, int n_in,
                              void* d_out, int out_size, void* d_ws, size_t ws_size,
                              hipStream_t stream) {
  const float* obj    = (const float*)d_in[0];
  const float* pred   = (const float*)d_in[1];
  const int*   edges  = (const int*)d_in[2];
  const float* pca_w1 = (const float*)d_in[3];
  const float* pca_b1 = (const float*)d_in[4];
  const float* clf_w1 = (const float*)d_in[5];
  const float* clf_b1 = (const float*)d_in[6];
  const float* bn_g1  = (const float*)d_in[7];
  const float* bn_b1  = (const float*)d_in[8];
  const float* pca_w2 = (const float*)d_in[9];
  const float* pca_b2 = (const float*)d_in[10];
  const float* clf_w2 = (const float*)d_in[11];
  const float* clf_b2 = (const float*)d_in[12];
  const float* bn_g2  = (const float*)d_in[13];
  const float* bn_b2  = (const float*)d_in[14];
  float* outp = (float*)d_out;

  char* ws = (char*)d_ws;
  bf_t* Xh   = (bf_t*)ws;
  bf_t* Uh2  = (bf_t*)(ws + 81920000);
  float* PL  = (float*)(ws + 102400000);
  bf_t* Uh1  = (bf_t*)(ws + 102400000);   // overlays PL (disjoint lifetimes)
  bf_t* Wt1  = (bf_t*)(ws + 122880000);
  bf_t* Wt2  = (bf_t*)(ws + 123273216);
  bf_t* Wt3  = (bf_t*)(ws + 124059648);
  bf_t* Wt4  = (bf_t*)(ws + 124321792);
  int* I     = (int*)(ws + 124583936);
  int* cnt_s  = I;            int* cnt_o  = I + 20000;
  int* offs_s = I + 40000;    int* offs_o = I + 60001;
  int* cur_o  = I + 80002;    int* srcs   = I + 100002;

  hipMemsetAsync(cnt_s, 0, 160000, stream);
  count_kernel<<<313, 256, 0, stream>>>(edges, cnt_s, cnt_o);
  scan_kernel<<<2, 1024, 0, stream>>>(cnt_s, cnt_o, offs_s, offs_o, cur_o);
  fill_kernel<<<313, 256, 0, stream>>>(edges, cur_o, srcs);

  transpose_cvt<<<dim3(16, 12), dim3(32, 8), 0, stream>>>(pca_w1, Wt1, 384, 512);
  transpose_cvt<<<dim3(24, 16), dim3(32, 8), 0, stream>>>(clf_w1, Wt2, 512, 768);
  transpose_cvt<<<dim3(16, 8),  dim3(32, 8), 0, stream>>>(pca_w2, Wt3, 256, 512);
  transpose_cvt<<<dim3(8, 16),  dim3(32, 8), 0, stream>>>(clf_w2, Wt4, 512, 256);

  // ---- phase 1 ----
  gemm_mfma<0><<<dim3(4, 625), 256, 0, stream>>>(nullptr, nullptr, nullptr, obj, pred, edges,
                                                 Wt1, pca_b1, nullptr, nullptr,
                                                 Xh, nullptr, nullptr, T_N, 512, 384);
  rout_layer<<<5000, 256, 0, stream>>>(Xh, Uh1, offs_o, srcs, O_N);
  rout_layer<<<5000, 256, 0, stream>>>(Uh1, Uh2, offs_o, srcs, O_N);
  hipMemsetAsync(PL, 0, 20480000, stream);
  gemm_mfma<1><<<dim3(6, 625), 256, 0, stream>>>(Uh2, Xh, nullptr, nullptr, nullptr, edges,
                                                 Wt2, clf_b1, bn_g1, bn_b1,
                                                 nullptr, outp + 5120000, PL, T_N, 768, 512);
  divide_kernel<<<O_N, 256, 0, stream>>>(PL, offs_s, offs_o);

  // ---- phase 2 ----
  gemm_mfma<2><<<dim3(4, 157), 256, 0, stream>>>(nullptr, nullptr, PL, nullptr, nullptr, nullptr,
                                                 Wt3, pca_b2, nullptr, nullptr,
                                                 Xh, nullptr, nullptr, O_N, 512, 256);
  rout_layer<<<5000, 256, 0, stream>>>(Xh, Uh1, offs_o, srcs, O_N);
  rout_layer<<<5000, 256, 0, stream>>>(Uh1, Uh2, offs_o, srcs, O_N);
  gemm_mfma<3><<<dim3(2, 157), 256, 0, stream>>>(Uh2, nullptr, nullptr, nullptr, nullptr, nullptr,
                                                 Wt4, clf_b2, bn_g2, bn_b2,
                                                 nullptr, outp, nullptr, O_N, 256, 512);
}